// Round 17
// baseline (137.065 us; speedup 1.0000x reference)
//
#include <hip/hip_runtime.h>

#define T_LEN 16384
#define NBATCH 8
#define CINCH 64
#define MIDCH 128
#define TT 64
#define PLANE (NBATCH * CINCH * T_LEN)

typedef __attribute__((ext_vector_type(8))) short short8;
typedef __attribute__((ext_vector_type(4))) float f32x4;

union fragu { short8 s; __bf16 h[8]; };

// ---- LDS layout (phased reuse; peak 40192 B) ----  (R9 layout, frozen)
#define XR_OFF     0        // bf16 [80 col][128 B] swizzled           (0..10240)
#define XI_OFF     10240    //                                          (..20480)
#define PART1_OFF  20480    // f32x4 [4][80]                            (..25600)
#define STATS1_OFF 38912    // f32x4 [80]                               (..40192)
#define Y_OFF      0        // u32 [128 ch][76 col]                     (0..38912)
#define PART2_OFF  0        // f32x4 [4][64]                            (0..4096)
#define STATS2_OFF 38912    // f32x4 [64]                               (..39936)
#define ZR_OFF     0        // bf16 [64 col][256 B] swizzled            (0..16384)
#define ZI_OFF     16384    //                                          (..32768)
#define BO_OFF     0        // f32 out bounce [2][64 row][68 col]       (0..34816)
#define BO_ROW     68       // floats
#define BO_PLANE   17408    // bytes
#define LDS_BYTES  40192

__device__ __forceinline__ unsigned pk2(float a, float b) {
    unsigned short ua = __builtin_bit_cast(unsigned short, (__bf16)a);
    unsigned short ub = __builtin_bit_cast(unsigned short, (__bf16)b);
    return (unsigned)ua | ((unsigned)ub << 16);
}
__device__ __forceinline__ float lo2f(unsigned u) { unsigned v = u << 16; return __builtin_bit_cast(float, v); }
__device__ __forceinline__ float hi2f(unsigned u) { unsigned v = u & 0xffff0000u; return __builtin_bit_cast(float, v); }

// R17 = R14 with ONE change: __launch_bounds__ REMOVED (A/B on the attribute
// alone; source otherwise byte-identical to the stable 114.5us artifact).
// Rationale: VGPR 84 permits 6 waves/SIMD and LDS 40448B permits 4 blocks/CU,
// yet (256,3) measures only 30% occupancy. The waves-per-eu attribute
// influences allocation/scheduling beyond the register cap; no-bounds gives
// the allocator MORE freedom than the cap-168 regime that produced the clean
// 84-VGPR allocation (R10's spill was the cap-128 regime, a different case).
// No-spill tells: WRITE_SIZE must stay ~88MB, absmax 0.03125 exactly.
// If flat/regressed -> final answer is the R14 artifact with (256,3).
__global__
void cdc_mfma(const float* __restrict__ x_re, const float* __restrict__ x_im,
              const float* __restrict__ w_in_re, const float* __restrict__ w_in_im,
              const float* __restrict__ b_in_re, const float* __restrict__ b_in_im,
              const float* __restrict__ alpha_in,
              const float* __restrict__ ln_in_w, const float* __restrict__ ln_in_b,
              const float* __restrict__ dw_re, const float* __restrict__ dw_im,
              const float* __restrict__ db_re, const float* __restrict__ db_im,
              const float* __restrict__ alpha_out,
              const float* __restrict__ ln_out_w, const float* __restrict__ ln_out_b,
              const float* __restrict__ w_out_re, const float* __restrict__ w_out_im,
              const float* __restrict__ b_out_re, const float* __restrict__ b_out_im,
              float* __restrict__ out)
{
    __shared__ __align__(16) unsigned char LDS[LDS_BYTES];
    unsigned char* ldsb = LDS;

    const int tid = threadIdx.x;
    const int w  = tid >> 6;       // wave 0..3
    const int l  = tid & 63;       // lane
    const int li = l & 15;
    const int u  = l >> 4;

    const int b    = blockIdx.x >> 8;     // 256 tiles per batch
    const int tile = blockIdx.x & 255;
    const int t0   = tile * TT;

    const float* xr_base = x_re + (size_t)b * CINCH * T_LEN;
    const float* xi_base = x_im + (size_t)b * CINCH * T_LEN;

    // ========== P1: stage x -> XR/XI (bf16 [col][64ch] swizzled, u32-paired) ==
    #pragma unroll
    for (int i = 0; i < 8; ++i) {
        int ch = 2 * (w + 4 * i);          // even ch 0..62
        int cy = l;                        // cols 0..63
        int gt = t0 - 4 + cy;
        float v0r = 0.f, v1r = 0.f, v0i = 0.f, v1i = 0.f;
        if (gt >= 0 && gt < T_LEN) {
            v0r = xr_base[ch * T_LEN + gt];       v1r = xr_base[(ch + 1) * T_LEN + gt];
            v0i = xi_base[ch * T_LEN + gt];       v1i = xi_base[(ch + 1) * T_LEN + gt];
        }
        int s = (ch + 8 * cy) & 63;        // even slot
        *(unsigned*)(ldsb + XR_OFF + cy * 128 + s * 2) = pk2(v0r, v1r);
        *(unsigned*)(ldsb + XI_OFF + cy * 128 + s * 2) = pk2(v0i, v1i);
    }
    {   // cols 64..71
        int ch = 2 * (tid & 31);
        int cy = 64 + (tid >> 5);
        int gt = t0 - 4 + cy;
        float v0r = 0.f, v1r = 0.f, v0i = 0.f, v1i = 0.f;
        if (gt >= 0 && gt < T_LEN) {
            v0r = xr_base[ch * T_LEN + gt];       v1r = xr_base[(ch + 1) * T_LEN + gt];
            v0i = xi_base[ch * T_LEN + gt];       v1i = xi_base[(ch + 1) * T_LEN + gt];
        }
        int s = (ch + 8 * cy) & 63;
        *(unsigned*)(ldsb + XR_OFF + cy * 128 + s * 2) = pk2(v0r, v1r);
        *(unsigned*)(ldsb + XI_OFF + cy * 128 + s * 2) = pk2(v0i, v1i);
    }
    {   // zero cols 72..79
        int ch = 2 * (tid & 31);
        int cy = 72 + (tid >> 5);
        int s = (ch + 8 * cy) & 63;
        *(unsigned*)(ldsb + XR_OFF + cy * 128 + s * 2) = 0u;
        *(unsigned*)(ldsb + XI_OFF + cy * 128 + s * 2) = 0u;
    }
    __syncthreads();   // S1

    // ========= P2: GEMM-in (MFMA), ks-outer to halve fragment liveness =====
    f32x4 aR[2][5], aI[2][5];
    #pragma unroll
    for (int mt2 = 0; mt2 < 2; ++mt2) {
        int chb = (2 * w + mt2) * 16 + u * 4;
        f32x4 br, bi2;
        #pragma unroll
        for (int r = 0; r < 4; ++r) { br[r] = b_in_re[chb + r]; bi2[r] = b_in_im[chb + r]; }
        #pragma unroll
        for (int nt = 0; nt < 5; ++nt) { aR[mt2][nt] = br; aI[mt2][nt] = bi2; }
    }
    #pragma unroll
    for (int ks = 0; ks < 2; ++ks) {
        fragu fr2[2], fim2[2], fng2[2];
        #pragma unroll
        for (int mt2 = 0; mt2 < 2; ++mt2) {
            int row = (2 * w + mt2) * 16 + li;
            int k0 = ks * 32 + u * 8;
            f32x4 r0 = *(const f32x4*)(w_in_re + row * 64 + k0);
            f32x4 r1 = *(const f32x4*)(w_in_re + row * 64 + k0 + 4);
            f32x4 i0 = *(const f32x4*)(w_in_im + row * 64 + k0);
            f32x4 i1 = *(const f32x4*)(w_in_im + row * 64 + k0 + 4);
            #pragma unroll
            for (int j = 0; j < 4; ++j) {
                fr2[mt2].h[j]      = (__bf16)r0[j];
                fr2[mt2].h[4 + j]  = (__bf16)r1[j];
                fim2[mt2].h[j]     = (__bf16)i0[j];
                fim2[mt2].h[4 + j] = (__bf16)i1[j];
                fng2[mt2].h[j]     = (__bf16)(-i0[j]);
                fng2[mt2].h[4 + j] = (__bf16)(-i1[j]);
            }
        }
        #pragma unroll
        for (int nt = 0; nt < 5; ++nt) {
            int col = nt * 16 + li;
            int rowb = col * 128;
            int st = ((u * 8 + ks * 32 + 8 * col) & 63) * 2;
            short8 xr8 = *(const short8*)(ldsb + XR_OFF + rowb + st);
            short8 xi8 = *(const short8*)(ldsb + XI_OFF + rowb + st);
            #pragma unroll
            for (int mt2 = 0; mt2 < 2; ++mt2) {
                aR[mt2][nt] = __builtin_amdgcn_mfma_f32_16x16x32_bf16(fr2[mt2].s,  xr8, aR[mt2][nt], 0, 0, 0);
                aR[mt2][nt] = __builtin_amdgcn_mfma_f32_16x16x32_bf16(fng2[mt2].s, xi8, aR[mt2][nt], 0, 0, 0);
                aI[mt2][nt] = __builtin_amdgcn_mfma_f32_16x16x32_bf16(fr2[mt2].s,  xi8, aI[mt2][nt], 0, 0, 0);
                aI[mt2][nt] = __builtin_amdgcn_mfma_f32_16x16x32_bf16(fim2[mt2].s, xr8, aI[mt2][nt], 0, 0, 0);
            }
        }
    }

    // PReLU(alpha_in) in regs + per-column partial sums for LN-in
    {
        float a1 = alpha_in[0];
        #pragma unroll
        for (int mt2 = 0; mt2 < 2; ++mt2)
            #pragma unroll
            for (int nt = 0; nt < 5; ++nt)
                #pragma unroll
                for (int r = 0; r < 4; ++r) {
                    float vr = aR[mt2][nt][r]; aR[mt2][nt][r] = vr >= 0.f ? vr : a1 * vr;
                    float vi = aI[mt2][nt][r]; aI[mt2][nt][r] = vi >= 0.f ? vi : a1 * vi;
                }
    }
    #pragma unroll
    for (int nt = 0; nt < 5; ++nt) {
        float sr = 0.f, qr = 0.f, si = 0.f, qi = 0.f;
        #pragma unroll
        for (int mt2 = 0; mt2 < 2; ++mt2)
            #pragma unroll
            for (int r = 0; r < 4; ++r) {
                float vr = aR[mt2][nt][r], vi = aI[mt2][nt][r];
                sr += vr; qr += vr * vr; si += vi; qi += vi * vi;
            }
        sr += __shfl_xor(sr, 16); sr += __shfl_xor(sr, 32);
        qr += __shfl_xor(qr, 16); qr += __shfl_xor(qr, 32);
        si += __shfl_xor(si, 16); si += __shfl_xor(si, 32);
        qi += __shfl_xor(qi, 16); qi += __shfl_xor(qi, 32);
        if (u == 0) {
            int col = nt * 16 + li;
            f32x4 v; v[0] = sr; v[1] = qr; v[2] = si; v[3] = qi;
            *(f32x4*)(ldsb + PART1_OFF + (w * 80 + col) * 16) = v;
        }
    }
    __syncthreads();   // S2
    if (tid < 80) {
        float SR = 0.f, QR = 0.f, SI = 0.f, QI = 0.f;
        #pragma unroll
        for (int ww = 0; ww < 4; ++ww) {
            f32x4 v = *(const f32x4*)(ldsb + PART1_OFF + (ww * 80 + tid) * 16);
            SR += v[0]; QR += v[1]; SI += v[2]; QI += v[3];
        }
        float mur = SR * 0.0078125f, mui = SI * 0.0078125f;
        f32x4 s4;
        s4[0] = mur;
        s4[1] = rsqrtf(QR * 0.0078125f - mur * mur + 1e-5f);
        s4[2] = mui;
        s4[3] = rsqrtf(QI * 0.0078125f - mui * mui + 1e-5f);
        *(f32x4*)(ldsb + STATS1_OFF + tid * 16) = s4;
    }
    __syncthreads();   // S3

    // ========== P4: LN-in apply + write Y (u32-packed bf16 [ch][76]) =======
    {
        float lw[2][4], lb[2][4];
        #pragma unroll
        for (int mt2 = 0; mt2 < 2; ++mt2) {
            int chb = (2 * w + mt2) * 16 + u * 4;
            #pragma unroll
            for (int r = 0; r < 4; ++r) { lw[mt2][r] = ln_in_w[chb + r]; lb[mt2][r] = ln_in_b[chb + r]; }
        }
        #pragma unroll
        for (int nt = 0; nt < 5; ++nt) {
            int col = nt * 16 + li;
            if (col < 72) {
                f32x4 sp = *(const f32x4*)(ldsb + STATS1_OFF + col * 16);
                int gt = t0 - 4 + col;
                bool valid = (gt >= 0) && (gt < T_LEN);
                #pragma unroll
                for (int mt2 = 0; mt2 < 2; ++mt2) {
                    int chb = (2 * w + mt2) * 16 + u * 4;
                    #pragma unroll
                    for (int r = 0; r < 4; ++r) {
                        float yr = valid ? ((aR[mt2][nt][r] - sp[0]) * sp[1] * lw[mt2][r] + lb[mt2][r]) : 0.f;
                        float yi = valid ? ((aI[mt2][nt][r] - sp[2]) * sp[3] * lw[mt2][r] + lb[mt2][r]) : 0.f;
                        *(unsigned*)(ldsb + Y_OFF + ((chb + r) * 76 + col) * 4) = pk2(yr, yi);
                    }
                }
            }
        }
    }
    __syncthreads();   // S4a: Y complete before any lane reads it

    // ====== P5: dconv0 (redundant, in registers) + dconv1 + PReLU ==========
    float g2r[32], g2i[32];
    {
        const int cb = w * 32;
        const float a2 = alpha_out[0];
        const bool lo_ok = (t0 - 2 + l) >= 0;      // z1 tap at storage l
        const bool hi_ok = (t0 + 2 + l) < T_LEN;   // z1 tap at storage l+4
        float sr = 0.f, qr = 0.f, si = 0.f, qi = 0.f;
        #pragma unroll
        for (int i = 0; i < 32; ++i) {
            const int ch = cb + i;
            const unsigned* yrow = (const unsigned*)(ldsb + Y_OFF + ch * 76 * 4);
            float w1r0 = dw_re[ch*3+0], w1r1 = dw_re[ch*3+1], w1r2 = dw_re[ch*3+2];
            float w1i0 = dw_im[ch*3+0], w1i1 = dw_im[ch*3+1], w1i2 = dw_im[ch*3+2];
            float db1r = db_re[ch], db1i = db_im[ch];
            unsigned p0 = yrow[l], p1 = yrow[l + 2], p2 = yrow[l + 4];
            unsigned p3 = yrow[l + 6], p4 = yrow[l + 8];
            float y0r = lo2f(p0), y0i = hi2f(p0);
            float y1r = lo2f(p1), y1i = hi2f(p1);
            float y2r = lo2f(p2), y2i = hi2f(p2);
            float y3r = lo2f(p3), y3i = hi2f(p3);
            float y4r = lo2f(p4), y4i = hi2f(p4);
            float zar = db1r + w1r0*y0r - w1i0*y0i + w1r1*y1r - w1i1*y1i + w1r2*y2r - w1i2*y2i;
            float zai = db1i + w1r0*y0i + w1i0*y0r + w1r1*y1i + w1i1*y1r + w1r2*y2i + w1i2*y2r;
            zar = lo_ok ? zar : 0.f;  zai = lo_ok ? zai : 0.f;
            float zbr = db1r + w1r0*y1r - w1i0*y1i + w1r1*y2r - w1i1*y2i + w1r2*y3r - w1i2*y3i;
            float zbi = db1i + w1r0*y1i + w1i0*y1r + w1r1*y2i + w1i1*y2r + w1r2*y3i + w1i2*y3r;
            float zcr = db1r + w1r0*y2r - w1i0*y2i + w1r1*y3r - w1i1*y3i + w1r2*y4r - w1i2*y4i;
            float zci = db1i + w1r0*y2i + w1i0*y2r + w1r1*y3i + w1i1*y3r + w1r2*y4i + w1i2*y4r;
            zcr = hi_ok ? zcr : 0.f;  zci = hi_ok ? zci : 0.f;
            float w2r0 = dw_re[384+ch*3+0], w2r1 = dw_re[384+ch*3+1], w2r2 = dw_re[384+ch*3+2];
            float w2i0 = dw_im[384+ch*3+0], w2i1 = dw_im[384+ch*3+1], w2i2 = dw_im[384+ch*3+2];
            float db2r = db_re[128+ch], db2i = db_im[128+ch];
            float zr = db2r + w2r0*zar - w2i0*zai + w2r1*zbr - w2i1*zbi + w2r2*zcr - w2i2*zci;
            float zi = db2i + w2r0*zai + w2i0*zar + w2r1*zbi + w2i1*zbr + w2r2*zci + w2i2*zcr;
            zr = zr >= 0.f ? zr : a2 * zr;
            zi = zi >= 0.f ? zi : a2 * zi;
            g2r[i] = zr; g2i[i] = zi;
            sr += zr; qr += zr * zr; si += zi; qi += zi * zi;
        }
        __syncthreads();   // S4b: all Y reads done before PART2 overwrites
        f32x4 v; v[0] = sr; v[1] = qr; v[2] = si; v[3] = qi;
        *(f32x4*)(ldsb + PART2_OFF + (w * 64 + l) * 16) = v;
    }
    __syncthreads();   // S5
    if (tid < 64) {
        float SR = 0.f, QR = 0.f, SI = 0.f, QI = 0.f;
        #pragma unroll
        for (int ww = 0; ww < 4; ++ww) {
            f32x4 v = *(const f32x4*)(ldsb + PART2_OFF + (ww * 64 + tid) * 16);
            SR += v[0]; QR += v[1]; SI += v[2]; QI += v[3];
        }
        float mur = SR * 0.0078125f, mui = SI * 0.0078125f;
        f32x4 s4;
        s4[0] = mur;
        s4[1] = rsqrtf(QR * 0.0078125f - mur * mur + 1e-5f);
        s4[2] = mui;
        s4[3] = rsqrtf(QI * 0.0078125f - mui * mui + 1e-5f);
        *(f32x4*)(ldsb + STATS2_OFF + tid * 16) = s4;
    }
    __syncthreads();   // S6

    // ========== P8: LN-out apply + write ZR/ZI ([col][128ch] swizzled) =====
    {
        const int c2 = l;
        const int cb = w * 32;
        f32x4 sp = *(const f32x4*)(ldsb + STATS2_OFF + c2 * 16);
        #pragma unroll
        for (int i = 0; i < 32; ++i) {
            float lw = ln_out_w[cb + i], lb2 = ln_out_b[cb + i];
            g2r[i] = (g2r[i] - sp[0]) * sp[1] * lw + lb2;
            g2i[i] = (g2i[i] - sp[2]) * sp[3] * lw + lb2;
        }
        #pragma unroll
        for (int kb = 0; kb < 4; ++kb) {
            fragu hr, hi2;
            #pragma unroll
            for (int j = 0; j < 8; ++j) {
                hr.h[j]  = (__bf16)g2r[kb * 8 + j];
                hi2.h[j] = (__bf16)g2i[kb * 8 + j];
            }
            int st = ((cb + kb * 8 + 8 * c2) & 127) * 2;
            *(short8*)(ldsb + ZR_OFF + c2 * 256 + st) = hr.s;
            *(short8*)(ldsb + ZI_OFF + c2 * 256 + st) = hi2.s;
        }
    }
    __syncthreads();   // S7

    // ================= P9: GEMM-out (MFMA) ================================
    fragu gr[4], gim[4], gng[4];
    {
        int o = w * 16 + li;
        #pragma unroll
        for (int ks = 0; ks < 4; ++ks) {
            int k0 = ks * 32 + u * 8;
            f32x4 r0 = *(const f32x4*)(w_out_re + o * 128 + k0);
            f32x4 r1 = *(const f32x4*)(w_out_re + o * 128 + k0 + 4);
            f32x4 i0 = *(const f32x4*)(w_out_im + o * 128 + k0);
            f32x4 i1 = *(const f32x4*)(w_out_im + o * 128 + k0 + 4);
            #pragma unroll
            for (int j = 0; j < 4; ++j) {
                gr[ks].h[j]      = (__bf16)r0[j];
                gr[ks].h[4 + j]  = (__bf16)r1[j];
                gim[ks].h[j]     = (__bf16)i0[j];
                gim[ks].h[4 + j] = (__bf16)i1[j];
                gng[ks].h[j]     = (__bf16)(-i0[j]);
                gng[ks].h[4 + j] = (__bf16)(-i1[j]);
            }
        }
    }
    f32x4 oR[4], oI[4];
    {
        int ob = w * 16 + u * 4;
        f32x4 br, bi2;
        #pragma unroll
        for (int r = 0; r < 4; ++r) { br[r] = b_out_re[ob + r]; bi2[r] = b_out_im[ob + r]; }
        #pragma unroll
        for (int nt = 0; nt < 4; ++nt) { oR[nt] = br; oI[nt] = bi2; }
    }
    #pragma unroll
    for (int nt = 0; nt < 4; ++nt) {
        int col = nt * 16 + li;
        #pragma unroll
        for (int ks = 0; ks < 4; ++ks) {
            int k0 = ks * 32 + u * 8;
            int st = ((k0 + 8 * col) & 127) * 2;
            short8 zr8 = *(const short8*)(ldsb + ZR_OFF + col * 256 + st);
            short8 zi8 = *(const short8*)(ldsb + ZI_OFF + col * 256 + st);
            oR[nt] = __builtin_amdgcn_mfma_f32_16x16x32_bf16(gr[ks].s,  zr8, oR[nt], 0, 0, 0);
            oR[nt] = __builtin_amdgcn_mfma_f32_16x16x32_bf16(gng[ks].s, zi8, oR[nt], 0, 0, 0);
            oI[nt] = __builtin_amdgcn_mfma_f32_16x16x32_bf16(gr[ks].s,  zi8, oI[nt], 0, 0, 0);
            oI[nt] = __builtin_amdgcn_mfma_f32_16x16x32_bf16(gim[ks].s, zr8, oI[nt], 0, 0, 0);
        }
    }
    __syncthreads();   // S8: ZR/ZI reads done before bounce overwrites

    // ========== P10: bounce out tile -> LDS, then wide coalesced store =====
    {
        int ob = w * 16 + u * 4;
        #pragma unroll
        for (int nt = 0; nt < 4; ++nt) {
            int col = nt * 16 + li;
            #pragma unroll
            for (int r = 0; r < 4; ++r) {
                *(float*)(ldsb + BO_OFF + ((ob + r) * BO_ROW + col) * 4)            = oR[nt][r];
                *(float*)(ldsb + BO_OFF + BO_PLANE + ((ob + r) * BO_ROW + col) * 4) = oI[nt][r];
            }
        }
    }
    __syncthreads();   // S9
    {
        #pragma unroll
        for (int i = 0; i < 8; ++i) {
            int idx = i * 256 + tid;           // [0, 2048)
            int cc = idx & 15;                 // 16 float4 per row
            int oo = (idx >> 4) & 63;          // channel row
            int p  = idx >> 10;                // 0 = re, 1 = im
            f32x4 v = *(const f32x4*)(ldsb + BO_OFF + p * BO_PLANE + (oo * BO_ROW + cc * 4) * 4);
            const float* xsrc = p ? xi_base : xr_base;
            size_t off = (size_t)oo * T_LEN + t0 + cc * 4;
            f32x4 xv = *(const f32x4*)(xsrc + off);
            v[0] += xv[0]; v[1] += xv[1]; v[2] += xv[2]; v[3] += xv[3];
            *(f32x4*)(out + (size_t)p * PLANE + (size_t)b * CINCH * T_LEN + off) = v;
        }
    }
}

extern "C" void kernel_launch(void* const* d_in, const int* in_sizes, int n_in,
                              void* d_out, int out_size, void* d_ws, size_t ws_size,
                              hipStream_t stream) {
    (void)in_sizes; (void)n_in; (void)d_ws; (void)ws_size; (void)out_size;
    dim3 grid(NBATCH * (T_LEN / TT));   // 8 * 256 = 2048
    dim3 block(256);
    hipLaunchKernelGGL(cdc_mfma, grid, block, 0, stream,
        (const float*)d_in[0],  (const float*)d_in[1],  (const float*)d_in[2],
        (const float*)d_in[3],  (const float*)d_in[4],  (const float*)d_in[5],
        (const float*)d_in[6],  (const float*)d_in[7],  (const float*)d_in[8],
        (const float*)d_in[9],  (const float*)d_in[10], (const float*)d_in[11],
        (const float*)d_in[12], (const float*)d_in[13], (const float*)d_in[14],
        (const float*)d_in[15], (const float*)d_in[16], (const float*)d_in[17],
        (const float*)d_in[18], (const float*)d_in[19], (float*)d_out);
}

// Round 18
// 113.918 us; speedup vs baseline: 1.2032x; 1.2032x over previous
//
#include <hip/hip_runtime.h>

#define T_LEN 16384
#define NBATCH 8
#define CINCH 64
#define MIDCH 128
#define TT 64
#define PLANE (NBATCH * CINCH * T_LEN)

typedef __attribute__((ext_vector_type(8))) short short8;
typedef __attribute__((ext_vector_type(4))) float f32x4;

union fragu { short8 s; __bf16 h[8]; };

// ---- LDS layout (phased reuse; peak 40192 B) ----  (R9 layout, FINAL)
#define XR_OFF     0        // bf16 [80 col][128 B] swizzled           (0..10240)
#define XI_OFF     10240    //                                          (..20480)
#define PART1_OFF  20480    // f32x4 [4][80]                            (..25600)
#define STATS1_OFF 38912    // f32x4 [80]                               (..40192)
#define Y_OFF      0        // u32 [128 ch][76 col]                     (0..38912)
#define PART2_OFF  0        // f32x4 [4][64]                            (0..4096)
#define STATS2_OFF 38912    // f32x4 [64]                               (..39936)
#define ZR_OFF     0        // bf16 [64 col][256 B] swizzled            (0..16384)
#define ZI_OFF     16384    //                                          (..32768)
#define BO_OFF     0        // f32 out bounce [2][64 row][68 col]       (0..34816)
#define BO_ROW     68       // floats
#define BO_PLANE   17408    // bytes
#define LDS_BYTES  40192

__device__ __forceinline__ unsigned pk2(float a, float b) {
    unsigned short ua = __builtin_bit_cast(unsigned short, (__bf16)a);
    unsigned short ub = __builtin_bit_cast(unsigned short, (__bf16)b);
    return (unsigned)ua | ((unsigned)ub << 16);
}
__device__ __forceinline__ float lo2f(unsigned u) { unsigned v = u << 16; return __builtin_bit_cast(float, v); }
__device__ __forceinline__ float hi2f(unsigned u) { unsigned v = u & 0xffff0000u; return __builtin_bit_cast(float, v); }

// FINAL ARTIFACT (R9/R14 equilibrium): 114.5us timed, absmax 0.03125,
// VGPR 84, no spill, WRITE_SIZE == output size. 5.0x over round-1 fp32.
// Launch-bounds sweep completed R17: default(uncapped)->VGPR 64+spill
// (137us); (256,4) cap128->spill (135us); (256,3) cap168->clean 84-VGPR
// (114.5us, unique spill-free operating point).
// Other HW-verified lessons: ks-outer P2 = low liveness; x-in-regs across
// the phase chain spills (R12); stats restructure collapses occupancy via
// scratch (R13); dconv rewrites fail correctness via LN-out's ~100x
// variance amplification (R5/R15). Latency-bound at 19% HBM / 5.9% Mfma;
// further gains need a pipelined rewrite this codegen rejects piecewise.
__global__ __launch_bounds__(256, 3)
void cdc_mfma(const float* __restrict__ x_re, const float* __restrict__ x_im,
              const float* __restrict__ w_in_re, const float* __restrict__ w_in_im,
              const float* __restrict__ b_in_re, const float* __restrict__ b_in_im,
              const float* __restrict__ alpha_in,
              const float* __restrict__ ln_in_w, const float* __restrict__ ln_in_b,
              const float* __restrict__ dw_re, const float* __restrict__ dw_im,
              const float* __restrict__ db_re, const float* __restrict__ db_im,
              const float* __restrict__ alpha_out,
              const float* __restrict__ ln_out_w, const float* __restrict__ ln_out_b,
              const float* __restrict__ w_out_re, const float* __restrict__ w_out_im,
              const float* __restrict__ b_out_re, const float* __restrict__ b_out_im,
              float* __restrict__ out)
{
    __shared__ __align__(16) unsigned char LDS[LDS_BYTES];
    unsigned char* ldsb = LDS;

    const int tid = threadIdx.x;
    const int w  = tid >> 6;       // wave 0..3
    const int l  = tid & 63;       // lane
    const int li = l & 15;
    const int u  = l >> 4;

    const int b    = blockIdx.x >> 8;     // 256 tiles per batch
    const int tile = blockIdx.x & 255;
    const int t0   = tile * TT;

    const float* xr_base = x_re + (size_t)b * CINCH * T_LEN;
    const float* xi_base = x_im + (size_t)b * CINCH * T_LEN;

    // ========== P1: stage x -> XR/XI (bf16 [col][64ch] swizzled, u32-paired) ==
    #pragma unroll
    for (int i = 0; i < 8; ++i) {
        int ch = 2 * (w + 4 * i);          // even ch 0..62
        int cy = l;                        // cols 0..63
        int gt = t0 - 4 + cy;
        float v0r = 0.f, v1r = 0.f, v0i = 0.f, v1i = 0.f;
        if (gt >= 0 && gt < T_LEN) {
            v0r = xr_base[ch * T_LEN + gt];       v1r = xr_base[(ch + 1) * T_LEN + gt];
            v0i = xi_base[ch * T_LEN + gt];       v1i = xi_base[(ch + 1) * T_LEN + gt];
        }
        int s = (ch + 8 * cy) & 63;        // even slot
        *(unsigned*)(ldsb + XR_OFF + cy * 128 + s * 2) = pk2(v0r, v1r);
        *(unsigned*)(ldsb + XI_OFF + cy * 128 + s * 2) = pk2(v0i, v1i);
    }
    {   // cols 64..71
        int ch = 2 * (tid & 31);
        int cy = 64 + (tid >> 5);
        int gt = t0 - 4 + cy;
        float v0r = 0.f, v1r = 0.f, v0i = 0.f, v1i = 0.f;
        if (gt >= 0 && gt < T_LEN) {
            v0r = xr_base[ch * T_LEN + gt];       v1r = xr_base[(ch + 1) * T_LEN + gt];
            v0i = xi_base[ch * T_LEN + gt];       v1i = xi_base[(ch + 1) * T_LEN + gt];
        }
        int s = (ch + 8 * cy) & 63;
        *(unsigned*)(ldsb + XR_OFF + cy * 128 + s * 2) = pk2(v0r, v1r);
        *(unsigned*)(ldsb + XI_OFF + cy * 128 + s * 2) = pk2(v0i, v1i);
    }
    {   // zero cols 72..79
        int ch = 2 * (tid & 31);
        int cy = 72 + (tid >> 5);
        int s = (ch + 8 * cy) & 63;
        *(unsigned*)(ldsb + XR_OFF + cy * 128 + s * 2) = 0u;
        *(unsigned*)(ldsb + XI_OFF + cy * 128 + s * 2) = 0u;
    }
    __syncthreads();   // S1

    // ========= P2: GEMM-in (MFMA), ks-outer to halve fragment liveness =====
    f32x4 aR[2][5], aI[2][5];
    #pragma unroll
    for (int mt2 = 0; mt2 < 2; ++mt2) {
        int chb = (2 * w + mt2) * 16 + u * 4;
        f32x4 br, bi2;
        #pragma unroll
        for (int r = 0; r < 4; ++r) { br[r] = b_in_re[chb + r]; bi2[r] = b_in_im[chb + r]; }
        #pragma unroll
        for (int nt = 0; nt < 5; ++nt) { aR[mt2][nt] = br; aI[mt2][nt] = bi2; }
    }
    #pragma unroll
    for (int ks = 0; ks < 2; ++ks) {
        fragu fr2[2], fim2[2], fng2[2];
        #pragma unroll
        for (int mt2 = 0; mt2 < 2; ++mt2) {
            int row = (2 * w + mt2) * 16 + li;
            int k0 = ks * 32 + u * 8;
            f32x4 r0 = *(const f32x4*)(w_in_re + row * 64 + k0);
            f32x4 r1 = *(const f32x4*)(w_in_re + row * 64 + k0 + 4);
            f32x4 i0 = *(const f32x4*)(w_in_im + row * 64 + k0);
            f32x4 i1 = *(const f32x4*)(w_in_im + row * 64 + k0 + 4);
            #pragma unroll
            for (int j = 0; j < 4; ++j) {
                fr2[mt2].h[j]      = (__bf16)r0[j];
                fr2[mt2].h[4 + j]  = (__bf16)r1[j];
                fim2[mt2].h[j]     = (__bf16)i0[j];
                fim2[mt2].h[4 + j] = (__bf16)i1[j];
                fng2[mt2].h[j]     = (__bf16)(-i0[j]);
                fng2[mt2].h[4 + j] = (__bf16)(-i1[j]);
            }
        }
        #pragma unroll
        for (int nt = 0; nt < 5; ++nt) {
            int col = nt * 16 + li;
            int rowb = col * 128;
            int st = ((u * 8 + ks * 32 + 8 * col) & 63) * 2;
            short8 xr8 = *(const short8*)(ldsb + XR_OFF + rowb + st);
            short8 xi8 = *(const short8*)(ldsb + XI_OFF + rowb + st);
            #pragma unroll
            for (int mt2 = 0; mt2 < 2; ++mt2) {
                aR[mt2][nt] = __builtin_amdgcn_mfma_f32_16x16x32_bf16(fr2[mt2].s,  xr8, aR[mt2][nt], 0, 0, 0);
                aR[mt2][nt] = __builtin_amdgcn_mfma_f32_16x16x32_bf16(fng2[mt2].s, xi8, aR[mt2][nt], 0, 0, 0);
                aI[mt2][nt] = __builtin_amdgcn_mfma_f32_16x16x32_bf16(fr2[mt2].s,  xi8, aI[mt2][nt], 0, 0, 0);
                aI[mt2][nt] = __builtin_amdgcn_mfma_f32_16x16x32_bf16(fim2[mt2].s, xr8, aI[mt2][nt], 0, 0, 0);
            }
        }
    }

    // PReLU(alpha_in) in regs + per-column partial sums for LN-in
    {
        float a1 = alpha_in[0];
        #pragma unroll
        for (int mt2 = 0; mt2 < 2; ++mt2)
            #pragma unroll
            for (int nt = 0; nt < 5; ++nt)
                #pragma unroll
                for (int r = 0; r < 4; ++r) {
                    float vr = aR[mt2][nt][r]; aR[mt2][nt][r] = vr >= 0.f ? vr : a1 * vr;
                    float vi = aI[mt2][nt][r]; aI[mt2][nt][r] = vi >= 0.f ? vi : a1 * vi;
                }
    }
    #pragma unroll
    for (int nt = 0; nt < 5; ++nt) {
        float sr = 0.f, qr = 0.f, si = 0.f, qi = 0.f;
        #pragma unroll
        for (int mt2 = 0; mt2 < 2; ++mt2)
            #pragma unroll
            for (int r = 0; r < 4; ++r) {
                float vr = aR[mt2][nt][r], vi = aI[mt2][nt][r];
                sr += vr; qr += vr * vr; si += vi; qi += vi * vi;
            }
        sr += __shfl_xor(sr, 16); sr += __shfl_xor(sr, 32);
        qr += __shfl_xor(qr, 16); qr += __shfl_xor(qr, 32);
        si += __shfl_xor(si, 16); si += __shfl_xor(si, 32);
        qi += __shfl_xor(qi, 16); qi += __shfl_xor(qi, 32);
        if (u == 0) {
            int col = nt * 16 + li;
            f32x4 v; v[0] = sr; v[1] = qr; v[2] = si; v[3] = qi;
            *(f32x4*)(ldsb + PART1_OFF + (w * 80 + col) * 16) = v;
        }
    }
    __syncthreads();   // S2
    if (tid < 80) {
        float SR = 0.f, QR = 0.f, SI = 0.f, QI = 0.f;
        #pragma unroll
        for (int ww = 0; ww < 4; ++ww) {
            f32x4 v = *(const f32x4*)(ldsb + PART1_OFF + (ww * 80 + tid) * 16);
            SR += v[0]; QR += v[1]; SI += v[2]; QI += v[3];
        }
        float mur = SR * 0.0078125f, mui = SI * 0.0078125f;
        f32x4 s4;
        s4[0] = mur;
        s4[1] = rsqrtf(QR * 0.0078125f - mur * mur + 1e-5f);
        s4[2] = mui;
        s4[3] = rsqrtf(QI * 0.0078125f - mui * mui + 1e-5f);
        *(f32x4*)(ldsb + STATS1_OFF + tid * 16) = s4;
    }
    __syncthreads();   // S3

    // ========== P4: LN-in apply + write Y (u32-packed bf16 [ch][76]) =======
    {
        float lw[2][4], lb[2][4];
        #pragma unroll
        for (int mt2 = 0; mt2 < 2; ++mt2) {
            int chb = (2 * w + mt2) * 16 + u * 4;
            #pragma unroll
            for (int r = 0; r < 4; ++r) { lw[mt2][r] = ln_in_w[chb + r]; lb[mt2][r] = ln_in_b[chb + r]; }
        }
        #pragma unroll
        for (int nt = 0; nt < 5; ++nt) {
            int col = nt * 16 + li;
            if (col < 72) {
                f32x4 sp = *(const f32x4*)(ldsb + STATS1_OFF + col * 16);
                int gt = t0 - 4 + col;
                bool valid = (gt >= 0) && (gt < T_LEN);
                #pragma unroll
                for (int mt2 = 0; mt2 < 2; ++mt2) {
                    int chb = (2 * w + mt2) * 16 + u * 4;
                    #pragma unroll
                    for (int r = 0; r < 4; ++r) {
                        float yr = valid ? ((aR[mt2][nt][r] - sp[0]) * sp[1] * lw[mt2][r] + lb[mt2][r]) : 0.f;
                        float yi = valid ? ((aI[mt2][nt][r] - sp[2]) * sp[3] * lw[mt2][r] + lb[mt2][r]) : 0.f;
                        *(unsigned*)(ldsb + Y_OFF + ((chb + r) * 76 + col) * 4) = pk2(yr, yi);
                    }
                }
            }
        }
    }
    __syncthreads();   // S4a: Y complete before any lane reads it

    // ====== P5: dconv0 (redundant, in registers) + dconv1 + PReLU ==========
    float g2r[32], g2i[32];
    {
        const int cb = w * 32;
        const float a2 = alpha_out[0];
        const bool lo_ok = (t0 - 2 + l) >= 0;      // z1 tap at storage l
        const bool hi_ok = (t0 + 2 + l) < T_LEN;   // z1 tap at storage l+4
        float sr = 0.f, qr = 0.f, si = 0.f, qi = 0.f;
        #pragma unroll
        for (int i = 0; i < 32; ++i) {
            const int ch = cb + i;
            const unsigned* yrow = (const unsigned*)(ldsb + Y_OFF + ch * 76 * 4);
            float w1r0 = dw_re[ch*3+0], w1r1 = dw_re[ch*3+1], w1r2 = dw_re[ch*3+2];
            float w1i0 = dw_im[ch*3+0], w1i1 = dw_im[ch*3+1], w1i2 = dw_im[ch*3+2];
            float db1r = db_re[ch], db1i = db_im[ch];
            unsigned p0 = yrow[l], p1 = yrow[l + 2], p2 = yrow[l + 4];
            unsigned p3 = yrow[l + 6], p4 = yrow[l + 8];
            float y0r = lo2f(p0), y0i = hi2f(p0);
            float y1r = lo2f(p1), y1i = hi2f(p1);
            float y2r = lo2f(p2), y2i = hi2f(p2);
            float y3r = lo2f(p3), y3i = hi2f(p3);
            float y4r = lo2f(p4), y4i = hi2f(p4);
            float zar = db1r + w1r0*y0r - w1i0*y0i + w1r1*y1r - w1i1*y1i + w1r2*y2r - w1i2*y2i;
            float zai = db1i + w1r0*y0i + w1i0*y0r + w1r1*y1i + w1i1*y1r + w1r2*y2i + w1i2*y2r;
            zar = lo_ok ? zar : 0.f;  zai = lo_ok ? zai : 0.f;
            float zbr = db1r + w1r0*y1r - w1i0*y1i + w1r1*y2r - w1i1*y2i + w1r2*y3r - w1i2*y3i;
            float zbi = db1i + w1r0*y1i + w1i0*y1r + w1r1*y2i + w1i1*y2r + w1r2*y3i + w1i2*y3r;
            float zcr = db1r + w1r0*y2r - w1i0*y2i + w1r1*y3r - w1i1*y3i + w1r2*y4r - w1i2*y4i;
            float zci = db1i + w1r0*y2i + w1i0*y2r + w1r1*y3i + w1i1*y3r + w1r2*y4i + w1i2*y4r;
            zcr = hi_ok ? zcr : 0.f;  zci = hi_ok ? zci : 0.f;
            float w2r0 = dw_re[384+ch*3+0], w2r1 = dw_re[384+ch*3+1], w2r2 = dw_re[384+ch*3+2];
            float w2i0 = dw_im[384+ch*3+0], w2i1 = dw_im[384+ch*3+1], w2i2 = dw_im[384+ch*3+2];
            float db2r = db_re[128+ch], db2i = db_im[128+ch];
            float zr = db2r + w2r0*zar - w2i0*zai + w2r1*zbr - w2i1*zbi + w2r2*zcr - w2i2*zci;
            float zi = db2i + w2r0*zai + w2i0*zar + w2r1*zbi + w2i1*zbr + w2r2*zci + w2i2*zcr;
            zr = zr >= 0.f ? zr : a2 * zr;
            zi = zi >= 0.f ? zi : a2 * zi;
            g2r[i] = zr; g2i[i] = zi;
            sr += zr; qr += zr * zr; si += zi; qi += zi * zi;
        }
        __syncthreads();   // S4b: all Y reads done before PART2 overwrites
        f32x4 v; v[0] = sr; v[1] = qr; v[2] = si; v[3] = qi;
        *(f32x4*)(ldsb + PART2_OFF + (w * 64 + l) * 16) = v;
    }
    __syncthreads();   // S5
    if (tid < 64) {
        float SR = 0.f, QR = 0.f, SI = 0.f, QI = 0.f;
        #pragma unroll
        for (int ww = 0; ww < 4; ++ww) {
            f32x4 v = *(const f32x4*)(ldsb + PART2_OFF + (ww * 64 + tid) * 16);
            SR += v[0]; QR += v[1]; SI += v[2]; QI += v[3];
        }
        float mur = SR * 0.0078125f, mui = SI * 0.0078125f;
        f32x4 s4;
        s4[0] = mur;
        s4[1] = rsqrtf(QR * 0.0078125f - mur * mur + 1e-5f);
        s4[2] = mui;
        s4[3] = rsqrtf(QI * 0.0078125f - mui * mui + 1e-5f);
        *(f32x4*)(ldsb + STATS2_OFF + tid * 16) = s4;
    }
    __syncthreads();   // S6

    // ========== P8: LN-out apply + write ZR/ZI ([col][128ch] swizzled) =====
    {
        const int c2 = l;
        const int cb = w * 32;
        f32x4 sp = *(const f32x4*)(ldsb + STATS2_OFF + c2 * 16);
        #pragma unroll
        for (int i = 0; i < 32; ++i) {
            float lw = ln_out_w[cb + i], lb2 = ln_out_b[cb + i];
            g2r[i] = (g2r[i] - sp[0]) * sp[1] * lw + lb2;
            g2i[i] = (g2i[i] - sp[2]) * sp[3] * lw + lb2;
        }
        #pragma unroll
        for (int kb = 0; kb < 4; ++kb) {
            fragu hr, hi2;
            #pragma unroll
            for (int j = 0; j < 8; ++j) {
                hr.h[j]  = (__bf16)g2r[kb * 8 + j];
                hi2.h[j] = (__bf16)g2i[kb * 8 + j];
            }
            int st = ((cb + kb * 8 + 8 * c2) & 127) * 2;
            *(short8*)(ldsb + ZR_OFF + c2 * 256 + st) = hr.s;
            *(short8*)(ldsb + ZI_OFF + c2 * 256 + st) = hi2.s;
        }
    }
    __syncthreads();   // S7

    // ================= P9: GEMM-out (MFMA) ================================
    fragu gr[4], gim[4], gng[4];
    {
        int o = w * 16 + li;
        #pragma unroll
        for (int ks = 0; ks < 4; ++ks) {
            int k0 = ks * 32 + u * 8;
            f32x4 r0 = *(const f32x4*)(w_out_re + o * 128 + k0);
            f32x4 r1 = *(const f32x4*)(w_out_re + o * 128 + k0 + 4);
            f32x4 i0 = *(const f32x4*)(w_out_im + o * 128 + k0);
            f32x4 i1 = *(const f32x4*)(w_out_im + o * 128 + k0 + 4);
            #pragma unroll
            for (int j = 0; j < 4; ++j) {
                gr[ks].h[j]      = (__bf16)r0[j];
                gr[ks].h[4 + j]  = (__bf16)r1[j];
                gim[ks].h[j]     = (__bf16)i0[j];
                gim[ks].h[4 + j] = (__bf16)i1[j];
                gng[ks].h[j]     = (__bf16)(-i0[j]);
                gng[ks].h[4 + j] = (__bf16)(-i1[j]);
            }
        }
    }
    f32x4 oR[4], oI[4];
    {
        int ob = w * 16 + u * 4;
        f32x4 br, bi2;
        #pragma unroll
        for (int r = 0; r < 4; ++r) { br[r] = b_out_re[ob + r]; bi2[r] = b_out_im[ob + r]; }
        #pragma unroll
        for (int nt = 0; nt < 4; ++nt) { oR[nt] = br; oI[nt] = bi2; }
    }
    #pragma unroll
    for (int nt = 0; nt < 4; ++nt) {
        int col = nt * 16 + li;
        #pragma unroll
        for (int ks = 0; ks < 4; ++ks) {
            int k0 = ks * 32 + u * 8;
            int st = ((k0 + 8 * col) & 127) * 2;
            short8 zr8 = *(const short8*)(ldsb + ZR_OFF + col * 256 + st);
            short8 zi8 = *(const short8*)(ldsb + ZI_OFF + col * 256 + st);
            oR[nt] = __builtin_amdgcn_mfma_f32_16x16x32_bf16(gr[ks].s,  zr8, oR[nt], 0, 0, 0);
            oR[nt] = __builtin_amdgcn_mfma_f32_16x16x32_bf16(gng[ks].s, zi8, oR[nt], 0, 0, 0);
            oI[nt] = __builtin_amdgcn_mfma_f32_16x16x32_bf16(gr[ks].s,  zi8, oI[nt], 0, 0, 0);
            oI[nt] = __builtin_amdgcn_mfma_f32_16x16x32_bf16(gim[ks].s, zr8, oI[nt], 0, 0, 0);
        }
    }
    __syncthreads();   // S8: ZR/ZI reads done before bounce overwrites

    // ========== P10: bounce out tile -> LDS, then wide coalesced store =====
    {
        int ob = w * 16 + u * 4;
        #pragma unroll
        for (int nt = 0; nt < 4; ++nt) {
            int col = nt * 16 + li;
            #pragma unroll
            for (int r = 0; r < 4; ++r) {
                *(float*)(ldsb + BO_OFF + ((ob + r) * BO_ROW + col) * 4)            = oR[nt][r];
                *(float*)(ldsb + BO_OFF + BO_PLANE + ((ob + r) * BO_ROW + col) * 4) = oI[nt][r];
            }
        }
    }
    __syncthreads();   // S9
    {
        #pragma unroll
        for (int i = 0; i < 8; ++i) {
            int idx = i * 256 + tid;           // [0, 2048)
            int cc = idx & 15;                 // 16 float4 per row
            int oo = (idx >> 4) & 63;          // channel row
            int p  = idx >> 10;                // 0 = re, 1 = im
            f32x4 v = *(const f32x4*)(ldsb + BO_OFF + p * BO_PLANE + (oo * BO_ROW + cc * 4) * 4);
            const float* xsrc = p ? xi_base : xr_base;
            size_t off = (size_t)oo * T_LEN + t0 + cc * 4;
            f32x4 xv = *(const f32x4*)(xsrc + off);
            v[0] += xv[0]; v[1] += xv[1]; v[2] += xv[2]; v[3] += xv[3];
            *(f32x4*)(out + (size_t)p * PLANE + (size_t)b * CINCH * T_LEN + off) = v;
        }
    }
}

extern "C" void kernel_launch(void* const* d_in, const int* in_sizes, int n_in,
                              void* d_out, int out_size, void* d_ws, size_t ws_size,
                              hipStream_t stream) {
    (void)in_sizes; (void)n_in; (void)d_ws; (void)ws_size; (void)out_size;
    dim3 grid(NBATCH * (T_LEN / TT));   // 8 * 256 = 2048
    dim3 block(256);
    hipLaunchKernelGGL(cdc_mfma, grid, block, 0, stream,
        (const float*)d_in[0],  (const float*)d_in[1],  (const float*)d_in[2],
        (const float*)d_in[3],  (const float*)d_in[4],  (const float*)d_in[5],
        (const float*)d_in[6],  (const float*)d_in[7],  (const float*)d_in[8],
        (const float*)d_in[9],  (const float*)d_in[10], (const float*)d_in[11],
        (const float*)d_in[12], (const float*)d_in[13], (const float*)d_in[14],
        (const float*)d_in[15], (const float*)d_in[16], (const float*)d_in[17],
        (const float*)d_in[18], (const float*)d_in[19], (float*)d_out);
}